// Round 9
// baseline (873.890 us; speedup 1.0000x reference)
//
#include <hip/hip_runtime.h>
#include <math.h>

// Problem constants (fixed by reference setup)
#define NN 50000
#define EE 400000
#define CINV 32
#define KKEEP 25000          // ceil(0.5*N)
#define SEQL 5
#define HASH_BITS 20
#define HASH_SIZE (1u<<HASH_BITS)
#define HASH_MASK (HASH_SIZE-1u)
#define HEMPTY 0xFFFFFFFFu
#define PSB 196              // ceil(NN/256)

typedef float vf4 __attribute__((ext_vector_type(4)));

__device__ __forceinline__ float sigm(float x){ return __builtin_amdgcn_rcpf(1.f+__expf(-x)); }
__device__ __forceinline__ float ftanh(float x){ return 1.f - 2.f*__builtin_amdgcn_rcpf(1.f+__expf(2.f*x)); }

// ---------------- merged init (+ LSTM weight prep) ----------------
// WT/bsum are PERMUTED so k_xw emits XW interleaved: XW[n][ch*4+g].
__global__ void k_init(uint2* __restrict__ hash, unsigned* __restrict__ hist,
                       int* __restrict__ degcnt, int* __restrict__ diagint,
                       int* __restrict__ fillc,
                       unsigned* scal, unsigned long long* selp,
                       const float* __restrict__ w0, const float* __restrict__ b0i,
                       const float* __restrict__ b0h, const float* __restrict__ wf,
                       const float* __restrict__ bfi, const float* __restrict__ bfh,
                       float* __restrict__ WT0, float* __restrict__ WTf,
                       float* __restrict__ bs0, float* __restrict__ bsf){
  int i = blockIdx.x*256 + threadIdx.x;
  if (i < (int)HASH_SIZE) hash[i] = make_uint2(HEMPTY, 0u);
  if (i < 4*65536) hist[i] = 0u;
  if (i < NN){ degcnt[i]=0; diagint[i]=0; fillc[i]=0; }
  if (i < 256*64){
    int r = i>>6, k = i&63;
    int dst = k*256 + (r&63)*4 + (r>>6);   // [k][ch][gate]
    WT0[dst] = w0[i];
    WTf[dst] = wf[i];
  }
  if (i < 256){
    int dst = (i&63)*4 + (i>>6);           // [ch][gate]
    bs0[dst]=b0i[i]+b0h[i]; bsf[dst]=bfi[i]+bfh[i];
  }
  if (i == 0){ scal[0]=0u; scal[1]=0u; scal[3]=KKEEP; selp[0]=0ull; }
}

// ---------------- phase2: degcnt + hash build + mask detect + GCN0 matmul ----------------
__global__ void k_phase2(const int* __restrict__ row, const int* __restrict__ col,
                         const int* __restrict__ mp, int* __restrict__ degcnt,
                         uint2* __restrict__ tab, unsigned* scal,
                         const float* __restrict__ X, const float* __restrict__ W,
                         float* __restrict__ Y){
  int idx = blockIdx.x*256 + threadIdx.x;
  if (idx < EE){
    int c = col[idx];
    atomicAdd(&degcnt[c], 1);
    unsigned key = (unsigned)row[idx]*50000u + (unsigned)c;
    unsigned h = (key*2654435761u) >> (32-HASH_BITS);
    for(;;){
      unsigned old = atomicCAS(&tab[h].x, HEMPTY, key);
      if (old==HEMPTY || old==key){ atomicAdd(&tab[h].y, 1u); break; }
      h = (h+1)&HASH_MASK;
    }
  }
  if (idx < NN/4){ if ((unsigned)mp[idx] > 1u) atomicOr(&scal[1], 1u); }
  if (idx < NN*16){
    int i = idx>>4, fq = idx&15;
    const vf4* X4 = (const vf4*)&X[i*CINV];
    const vf4* W4 = (const vf4*)W;
    vf4 acc = {0.f,0.f,0.f,0.f};
    #pragma unroll
    for (int kq=0;kq<CINV/4;kq++){
      vf4 xv = X4[kq];
      #pragma unroll
      for (int u=0;u<4;u++) acc += xv[u] * W4[(kq*4+u)*16+fq];
    }
    ((vf4*)Y)[i*16+fq] = acc;
  }
}

// ---------------- DUAL prefix sum (indptr + SORTED mask compaction) + dinv0 ----------------
__global__ void k_psum1(const int* __restrict__ deg, const void* __restrict__ mp,
                        const unsigned* __restrict__ scal,
                        int* __restrict__ part, int* __restrict__ bsum,
                        int* __restrict__ mpart, int* __restrict__ mbsum,
                        float* __restrict__ dinv){
  __shared__ int sc[256];
  __shared__ int sm[256];
  int b = blockIdx.x, t = threadIdx.x, i = b*256+t;
  int v = (i<NN) ? deg[i] : 0;
  int mv = 0;
  if (i < NN){
    dinv[i] = rsqrtf((float)v + 2.0f);
    mv = scal[1] ? (int)(((const unsigned char*)mp)[i] != 0)
                 : (int)(((const int*)mp)[i] != 0);
  }
  sc[t] = v; sm[t] = mv; __syncthreads();
  for (int o=1;o<256;o<<=1){
    int x = (t>=o) ? sc[t-o] : 0;
    int y = (t>=o) ? sm[t-o] : 0;
    __syncthreads();
    sc[t] += x; sm[t] += y;
    __syncthreads();
  }
  if (i < NN){ part[i] = sc[t]-v; mpart[i] = sm[t]-mv; }
  if (t == 255){ bsum[b] = sc[255]; mbsum[b] = sm[255]; }
}
__global__ void k_psum3(const int* __restrict__ part, const int* __restrict__ bsum,
                        const int* __restrict__ mpart, const int* __restrict__ mbsum,
                        const void* __restrict__ mp, unsigned* __restrict__ scal,
                        int* __restrict__ indptr, int* __restrict__ mlist,
                        int* __restrict__ minv){
  __shared__ int sc[256];
  __shared__ int sm[256];
  int t = threadIdx.x;
  int v = (t<PSB) ? bsum[t] : 0;
  int w = (t<PSB) ? mbsum[t] : 0;
  sc[t] = v; sm[t] = w; __syncthreads();
  for (int o=1;o<256;o<<=1){
    int x = (t>=o) ? sc[t-o] : 0;
    int y = (t>=o) ? sm[t-o] : 0;
    __syncthreads();
    sc[t] += x; sm[t] += y;
    __syncthreads();
  }
  int bb = blockIdx.x;
  int ex  = sc[bb] - ((bb<PSB) ? bsum[bb] : 0);    // exclusive prefixes for this block
  int mex = sm[bb] - ((bb<PSB) ? mbsum[bb] : 0);
  int i = bb*256 + t;
  if (i < NN){
    indptr[i] = part[i] + ex;
    int mv = scal[1] ? (int)(((const unsigned char*)mp)[i] != 0)
                     : (int)(((const int*)mp)[i] != 0);
    if (mv){ int p = mpart[i] + mex; mlist[p] = i; minv[i] = p; }
    else minv[i] = -1;
  }
  if (i == 0){ indptr[NN] = EE; scal[0] = (unsigned)sm[255]; }
}

// ---------------- csr fill + A^2 diag ----------------
__global__ void k_phase4(const int* __restrict__ row, const int* __restrict__ col,
                         const int* __restrict__ indptr, int* __restrict__ fillc,
                         int* __restrict__ csr_r, const uint2* __restrict__ tab,
                         int* __restrict__ diagint){
  int idx = blockIdx.x*256 + threadIdx.x;
  if (idx >= EE) return;
  int r = row[idx], c = col[idx];
  int pos = indptr[c] + atomicAdd(&fillc[c], 1);
  csr_r[pos] = r;
  unsigned rkey = (unsigned)c*50000u + (unsigned)r;
  unsigned h = (rkey*2654435761u) >> (32-HASH_BITS);
  for(;;){
    unsigned kk = tab[h].x;
    if (kk==rkey){ atomicAdd(&diagint[r], (int)tab[h].y); break; }
    if (kk==HEMPTY) break;
    h = (h+1)&HASH_MASK;
  }
}

// ---------------- remaining matmul (up-GCN input) ----------------
__global__ void k_mm64v(const float* __restrict__ X, const float* __restrict__ W, float* __restrict__ Y){
  int idx = blockIdx.x*256 + threadIdx.x;
  if (idx >= NN*16) return;
  int i = idx>>4, fq = idx&15;
  const vf4* X4 = (const vf4*)&X[i*64];
  const vf4* W4 = (const vf4*)W;
  vf4 acc = {0.f,0.f,0.f,0.f};
  #pragma unroll
  for (int kq=0;kq<16;kq++){
    vf4 xv = X4[kq];
    #pragma unroll
    for (int u=0;u<4;u++) acc += xv[u] * W4[(kq*4+u)*16+fq];
  }
  ((vf4*)Y)[i*16+fq] = acc;
}

// ---------------- CSR gather GCN kernels (8-wide zero-padded, R16-proven) ----------------
__global__ void g_gcn0(const int* __restrict__ indptr, const int* __restrict__ csr_r,
                       const float* __restrict__ dinv, const float* __restrict__ H,
                       const float* __restrict__ b, const float* __restrict__ pw,
                       float* __restrict__ out, unsigned long long* __restrict__ keys,
                       float* __restrict__ score, unsigned* __restrict__ hist){
  int node = blockIdx.x*4 + (threadIdx.x>>6), lane = threadIdx.x&63;
  if (node >= NN) return;
  int s = __builtin_amdgcn_readfirstlane(indptr[node]);
  int e = __builtin_amdgcn_readfirstlane(indptr[node+1]);
  int deg = e - s;
  float a0=0.f,a1=0.f,a2=0.f,a3=0.f,a4=0.f,a5=0.f,a6=0.f,a7=0.f;
  for (int base=0; base<deg; base+=64){
    int take = min(64, deg-base);
    bool act = lane < take;
    int ii = act ? csr_r[s+base+lane] : 0;
    float dv = act ? dinv[ii] : 0.f;
    for (int j=0; j<take; j+=8){
      int   r0=__shfl(ii,j,64),   r1=__shfl(ii,j+1,64), r2=__shfl(ii,j+2,64), r3=__shfl(ii,j+3,64),
            r4=__shfl(ii,j+4,64), r5=__shfl(ii,j+5,64), r6=__shfl(ii,j+6,64), r7=__shfl(ii,j+7,64);
      float d0=__shfl(dv,j,64),   d1=__shfl(dv,j+1,64), d2=__shfl(dv,j+2,64), d3=__shfl(dv,j+3,64),
            d4=__shfl(dv,j+4,64), d5=__shfl(dv,j+5,64), d6=__shfl(dv,j+6,64), d7=__shfl(dv,j+7,64);
      a0 += d0*H[(size_t)r0*64+lane];
      a1 += d1*H[(size_t)r1*64+lane];
      a2 += d2*H[(size_t)r2*64+lane];
      a3 += d3*H[(size_t)r3*64+lane];
      a4 += d4*H[(size_t)r4*64+lane];
      a5 += d5*H[(size_t)r5*64+lane];
      a6 += d6*H[(size_t)r6*64+lane];
      a7 += d7*H[(size_t)r7*64+lane];
    }
  }
  float acc = ((a0+a1)+(a2+a3)) + ((a4+a5)+(a6+a7));
  float di = dinv[node];
  float v = di*acc + 2.f*di*di*H[(size_t)node*64+lane] + b[lane];
  float x1v = fmaxf(v, 0.f);
  out[(size_t)node*64+lane] = x1v;
  float pv = pw[lane];
  float nq = pv*pv;
  float dq = x1v*pv;
  for (int o=32;o;o>>=1){ nq += __shfl_down(nq, o, 64); dq += __shfl_down(dq, o, 64); }
  if (lane==0){
    float sv = tanhf(dq / sqrtf(nq));
    sv = sv + 0.0f;               // canonicalize -0 -> +0
    score[node] = sv;
    unsigned u = __float_as_uint(sv);
    unsigned asc = (u>>31) ? ~u : (u | 0x80000000u);
    unsigned desc = ~asc;
    keys[node] = (((unsigned long long)desc)<<32) | (unsigned)node;
    atomicAdd(&hist[desc>>16], 1u);      // radix round-0 histogram
  }
}
// t2: unconditional 8-wide (k_csgmm zero-fills dropped rows)
__global__ void g_t2(const int* __restrict__ indptr, const int* __restrict__ csr_r,
                     const float* __restrict__ dinv1, const float* __restrict__ hp,
                     float* __restrict__ t2){
  int node = blockIdx.x*4 + (threadIdx.x>>6), lane = threadIdx.x&63;
  if (node >= NN) return;
  int s = __builtin_amdgcn_readfirstlane(indptr[node]);
  int e = __builtin_amdgcn_readfirstlane(indptr[node+1]);
  int deg = e - s;
  float a0 = dinv1[node]*hp[(size_t)node*64+lane];   // self loop
  float a1=0.f,a2=0.f,a3=0.f,a4=0.f,a5=0.f,a6=0.f,a7=0.f;
  for (int base=0; base<deg; base+=64){
    int take = min(64, deg-base);
    bool act = lane < take;
    int ii = act ? csr_r[s+base+lane] : 0;
    float dv = act ? dinv1[ii] : 0.f;
    for (int j=0; j<take; j+=8){
      int   r0=__shfl(ii,j,64),   r1=__shfl(ii,j+1,64), r2=__shfl(ii,j+2,64), r3=__shfl(ii,j+3,64),
            r4=__shfl(ii,j+4,64), r5=__shfl(ii,j+5,64), r6=__shfl(ii,j+6,64), r7=__shfl(ii,j+7,64);
      float d0=__shfl(dv,j,64),   d1=__shfl(dv,j+1,64), d2=__shfl(dv,j+2,64), d3=__shfl(dv,j+3,64),
            d4=__shfl(dv,j+4,64), d5=__shfl(dv,j+5,64), d6=__shfl(dv,j+6,64), d7=__shfl(dv,j+7,64);
      a0 += d0*hp[(size_t)r0*64+lane];
      a1 += d1*hp[(size_t)r1*64+lane];
      a2 += d2*hp[(size_t)r2*64+lane];
      a3 += d3*hp[(size_t)r3*64+lane];
      a4 += d4*hp[(size_t)r4*64+lane];
      a5 += d5*hp[(size_t)r5*64+lane];
      a6 += d6*hp[(size_t)r6*64+lane];
      a7 += d7*hp[(size_t)r7*64+lane];
    }
  }
  t2[(size_t)node*64+lane] = ((a0+a1)+(a2+a3)) + ((a4+a5)+(a6+a7));
}
// D[i] = (masked ? H0[minv[i]] : C[i]) + (kept ? relu(x2_i) : 0)
__global__ void g_agg2y(const int* __restrict__ indptr, const int* __restrict__ csr_r,
                        const float* __restrict__ t2, const float* __restrict__ hp,
                        const float* __restrict__ dinv1, const int* __restrict__ diagint,
                        const int* __restrict__ kp, const float* __restrict__ b1,
                        const float* __restrict__ C, const float* __restrict__ Hbuf,
                        const int* __restrict__ minv, float* __restrict__ D){
  int node = blockIdx.x*4 + (threadIdx.x>>6), lane = threadIdx.x&63;
  if (node >= NN) return;
  int mv = minv[node];
  float base = (mv >= 0) ? Hbuf[(size_t)mv*64+lane] : C[(size_t)node*64+lane];
  float add = 0.f;
  if (kp[node]){
    int s = __builtin_amdgcn_readfirstlane(indptr[node]);
    int e = __builtin_amdgcn_readfirstlane(indptr[node+1]);
    int deg = e - s;
    float a0 = t2[(size_t)node*64+lane];             // self loop
    float a1=0.f,a2=0.f,a3=0.f,a4=0.f,a5=0.f,a6=0.f,a7=0.f;
    for (int bs2=0; bs2<deg; bs2+=64){
      int take = min(64, deg-bs2);
      bool act = lane < take;
      int ii = act ? csr_r[s+bs2+lane] : 0;
      float wv = act ? 1.f : 0.f;                    // pad weight
      for (int j=0; j<take; j+=8){
        int   r0=__shfl(ii,j,64),   r1=__shfl(ii,j+1,64), r2=__shfl(ii,j+2,64), r3=__shfl(ii,j+3,64),
              r4=__shfl(ii,j+4,64), r5=__shfl(ii,j+5,64), r6=__shfl(ii,j+6,64), r7=__shfl(ii,j+7,64);
        float w0=__shfl(wv,j,64),   w1=__shfl(wv,j+1,64), w2=__shfl(wv,j+2,64), w3=__shfl(wv,j+3,64),
              w4=__shfl(wv,j+4,64), w5=__shfl(wv,j+5,64), w6=__shfl(wv,j+6,64), w7=__shfl(wv,j+7,64);
        a0 += w0*t2[(size_t)r0*64+lane];
        a1 += w1*t2[(size_t)r1*64+lane];
        a2 += w2*t2[(size_t)r2*64+lane];
        a3 += w3*t2[(size_t)r3*64+lane];
        a4 += w4*t2[(size_t)r4*64+lane];
        a5 += w5*t2[(size_t)r5*64+lane];
        a6 += w6*t2[(size_t)r6*64+lane];
        a7 += w7*t2[(size_t)r7*64+lane];
      }
    }
    float acc = ((a0+a1)+(a2+a3)) + ((a4+a5)+(a6+a7));
    float di = dinv1[node], hv = hp[(size_t)node*64+lane];
    float diag = (float)(diagint[node] + 1);
    float v = di*(acc - diag*di*hv) + 2.f*di*di*hv + b1[lane];
    add = fmaxf(v, 0.f);
  }
  D[(size_t)node*64+lane] = base + add;
}
__global__ void g_up(const int* __restrict__ indptr, const int* __restrict__ csr_r,
                     const float* __restrict__ dinv, const float* __restrict__ H,
                     const float* __restrict__ b, float* __restrict__ xo, float* __restrict__ out){
  int node = blockIdx.x*4 + (threadIdx.x>>6), lane = threadIdx.x&63;
  if (node >= NN) return;
  int s = __builtin_amdgcn_readfirstlane(indptr[node]);
  int e = __builtin_amdgcn_readfirstlane(indptr[node+1]);
  int deg = e - s;
  float a0=0.f,a1=0.f,a2=0.f,a3=0.f,a4=0.f,a5=0.f,a6=0.f,a7=0.f;
  for (int base=0; base<deg; base+=64){
    int take = min(64, deg-base);
    bool act = lane < take;
    int ii = act ? csr_r[s+base+lane] : 0;
    float dv = act ? dinv[ii] : 0.f;
    for (int j=0; j<take; j+=8){
      int   r0=__shfl(ii,j,64),   r1=__shfl(ii,j+1,64), r2=__shfl(ii,j+2,64), r3=__shfl(ii,j+3,64),
            r4=__shfl(ii,j+4,64), r5=__shfl(ii,j+5,64), r6=__shfl(ii,j+6,64), r7=__shfl(ii,j+7,64);
      float d0=__shfl(dv,j,64),   d1=__shfl(dv,j+1,64), d2=__shfl(dv,j+2,64), d3=__shfl(dv,j+3,64),
            d4=__shfl(dv,j+4,64), d5=__shfl(dv,j+5,64), d6=__shfl(dv,j+6,64), d7=__shfl(dv,j+7,64);
      a0 += d0*H[(size_t)r0*64+lane];
      a1 += d1*H[(size_t)r1*64+lane];
      a2 += d2*H[(size_t)r2*64+lane];
      a3 += d3*H[(size_t)r3*64+lane];
      a4 += d4*H[(size_t)r4*64+lane];
      a5 += d5*H[(size_t)r5*64+lane];
      a6 += d6*H[(size_t)r6*64+lane];
      a7 += d7*H[(size_t)r7*64+lane];
    }
  }
  float acc = ((a0+a1)+(a2+a3)) + ((a4+a5)+(a6+a7));
  float di = dinv[node];
  float v = di*acc + 2.f*di*di*H[(size_t)node*64+lane] + b[lane];
  xo[(size_t)node*64+lane] = v; out[(size_t)node*64+lane] = v;
}

// ---------------- TopK radix select (round 0 hist fused into g_gcn0) ----------------
__global__ void k_hist(const unsigned long long* __restrict__ keys, unsigned* __restrict__ hist,
                       const unsigned long long* __restrict__ selp, int round){
  int i = blockIdx.x*256 + threadIdx.x;
  if (i >= NN) return;
  unsigned long long key = keys[i];
  int shift = 48 - 16*round;
  if ((key>>(shift+16)) == selp[0])
    atomicAdd(&hist[(unsigned)((key>>shift)&0xFFFFull)], 1u);
}
__global__ void k_pick(const unsigned* __restrict__ hist, unsigned long long* selp, unsigned* scal){
  __shared__ unsigned csum[256];
  __shared__ unsigned bins[256];
  __shared__ int schunk;
  int t = threadIdx.x;
  const uint4* h4 = (const uint4*)(hist + t*256);
  unsigned s = 0;
  #pragma unroll 8
  for (int j=0;j<64;j++){ uint4 v = h4[j]; s += v.x+v.y+v.z+v.w; }
  csum[t] = s;
  __syncthreads();
  if (t==0){
    unsigned rem = scal[3];
    int chunk = 255;
    for (int c2=0;c2<256;c2++){ unsigned cc=csum[c2]; if (rem>cc) rem-=cc; else { chunk=c2; break; } }
    schunk = chunk; scal[3] = rem;
  }
  __syncthreads();
  bins[t] = hist[schunk*256 + t];
  __syncthreads();
  if (t==0){
    unsigned rem = scal[3];
    int bin = schunk*256 + 255;
    for (int b=0;b<256;b++){ unsigned hv=bins[b]; if (rem>hv) rem-=hv; else { bin = schunk*256 + b; break; } }
    selp[0] = (selp[0]<<16) | (unsigned long long)(unsigned)bin;
    scal[3] = rem;
  }
}
// pooled degree pass 1 (CSR gather): kp[i]; ts[i] = sum_{r->i} kp[r] + kp[i]
__global__ void k_tsg(const int* __restrict__ indptr, const int* __restrict__ csr_r,
                      const unsigned long long* __restrict__ keys,
                      const unsigned long long* __restrict__ selp,
                      int* __restrict__ kp, int* __restrict__ ts){
  int i = blockIdx.x*256 + threadIdx.x;
  if (i >= NN) return;
  unsigned long long sp = selp[0];
  int s = indptr[i], e = indptr[i+1];
  int self = (keys[i] <= sp) ? 1 : 0;
  kp[i] = self;
  int acc = self;
  for (int j=s;j<e;j++) acc += (keys[csr_r[j]] <= sp) ? 1 : 0;
  ts[i] = acc;
}
// pooled degree pass 2 + dinv1 MERGED with hp = (x1*score)@W1
// Dropped nodes WRITE ZERO rows (enables unguarded g_t2 gather).
__global__ void k_csgmm(const int* __restrict__ indptr, const int* __restrict__ csr_r,
                        const int* __restrict__ ts, const int* __restrict__ diagint,
                        const int* __restrict__ kp, float* __restrict__ dinv1,
                        const float* __restrict__ X, const float* __restrict__ W,
                        const float* __restrict__ sc, float* __restrict__ Y){
  int idx = blockIdx.x*256 + threadIdx.x;
  if (idx < NN*16){
    int i = idx>>4, fq = idx&15;
    if (!kp[i]){ vf4 z = {0.f,0.f,0.f,0.f}; ((vf4*)Y)[i*16+fq] = z; return; }
    const vf4* X4 = (const vf4*)&X[i*64];
    const vf4* W4 = (const vf4*)W;
    vf4 acc = {0.f,0.f,0.f,0.f};
    #pragma unroll
    for (int kq=0;kq<16;kq++){
      vf4 xv = X4[kq];
      #pragma unroll
      for (int u=0;u<4;u++) acc += xv[u] * W4[(kq*4+u)*16+fq];
    }
    acc *= sc[i];
    ((vf4*)Y)[i*16+fq] = acc;
  } else {
    int i = idx - NN*16;
    if (i >= NN) return;
    int s = indptr[i], e = indptr[i+1];
    int acc = ts[i];
    for (int j=s;j<e;j++) acc += ts[csr_r[j]];
    dinv1[i] = kp[i] ? rsqrtf((float)(acc - diagint[i] - 1) + 2.0f) : 0.f;
  }
}

// ---------------- LSTM part 1: XW[n] = src[n] @ W_ih^T + (b_ih+b_hh) ----------------
__global__ __launch_bounds__(256) void k_xw(const float* __restrict__ src,
        const float* __restrict__ WT, const float* __restrict__ bsum,
        float* __restrict__ XW){
  __shared__ vf4 Wl[4096];              // 64 KB
  int t = threadIdx.x;
  const vf4* Wg = (const vf4*)WT;
  for (int u=t; u<4096; u+=256) Wl[u] = Wg[u];
  int fq = t & 63, wv = t >> 6;
  vf4 bias = ((const vf4*)bsum)[fq];
  __syncthreads();
  for (int g = blockIdx.x*4 + wv; g < NN/4; g += gridDim.x*4){
    int n0 = g*4;
    const vf4* X4 = (const vf4*)&src[(size_t)n0*64];   // 4 rows x 16 vf4
    vf4 a0=bias, a1=bias, a2=bias, a3=bias;
    #pragma unroll 4
    for (int kq=0;kq<16;kq++){
      vf4 x0 = X4[kq], x1 = X4[16+kq], x2 = X4[32+kq], x3 = X4[48+kq];
      vf4 w0 = Wl[(kq*4+0)*64+fq];
      vf4 w1 = Wl[(kq*4+1)*64+fq];
      vf4 w2 = Wl[(kq*4+2)*64+fq];
      vf4 w3 = Wl[(kq*4+3)*64+fq];
      a0 += x0.x*w0 + x0.y*w1 + x0.z*w2 + x0.w*w3;
      a1 += x1.x*w0 + x1.y*w1 + x1.z*w2 + x1.w*w3;
      a2 += x2.x*w0 + x2.y*w1 + x2.z*w2 + x2.w*w3;
      a3 += x3.x*w0 + x3.y*w1 + x3.z*w2 + x3.w*w3;
    }
    vf4* Y = (vf4*)XW;
    Y[(size_t)n0*64 + fq]       = a0;
    Y[(size_t)n0*64 + 64 + fq]  = a1;
    Y[(size_t)n0*64 + 128 + fq] = a2;
    Y[(size_t)n0*64 + 192 + fq] = a3;
  }
}

// ---------------- LSTM part 2: recurrence, ONE NODE PER 128-THREAD BLOCK ----------------
// R18: 2 waves/node. Wave w holds W_hh rows for gates {2w,2w+1} of channel
// `lane` (32 vf4 = 128 regs; between R7's proven 64 and R10's failing 256).
// Per step: 16 LDS broadcast reads + 32 vf4 FMA per wave (serial chain ~1/3
// of R7 design), each wave writes its 2 hh-gate parts to parity-dbuf gx,
// ONE __syncthreads, then BOTH waves redundantly compute c,h (identical
// inputs -> bit-identical) so h never crosses waves: each wave keeps its own
// LDS h copy (same-wave RAW, lgkmcnt-ordered; R10-verified pattern).
__global__ __launch_bounds__(128) void k_rec(const float* __restrict__ XW,
        const float* __restrict__ whh, const float* __restrict__ bsum,
        const int* __restrict__ mlist, const unsigned* __restrict__ scal,
        float* __restrict__ dst, int scatter){
  int M = (int)scal[0];
  if (M < 0 || M > NN) M = 0;          // defensive (rocprof replay poisons scal)
  int task = blockIdx.x;
  if (task >= M) return;               // block-uniform early exit
  int w = threadIdx.x>>6, lane = threadIdx.x&63;
  // weight fill: rows (2w)*64+lane and (2w+1)*64+lane of whh (256x64)
  const vf4* gA = (const vf4*)&whh[(size_t)((2*w+0)*64+lane)*64];
  const vf4* gB = (const vf4*)&whh[(size_t)((2*w+1)*64+lane)*64];
  vf4 wh[32];
  #pragma unroll
  for (int j=0;j<16;j++){ wh[j] = gA[j]; wh[16+j] = gB[j]; }
  __shared__ __align__(16) float shh[2][64];   // per-wave h copy (same-wave RAW only)
  __shared__ float gx[2][4][64];               // hh-gate parts, dbuf by step parity
  int node = mlist[task];
  node = min(max(node, 0), NN-1);      // defensive vs poisoned mlist in replay
  const vf4* XW4 = (const vf4*)XW;
  vf4 bp = ((const vf4*)bsum)[lane];
  vf4 xs0, xs1, xs2, xs3, xs4;
  {
    int r0 = node - 4, r1 = node - 3;
    xs0 = (r0 >= 0) ? XW4[(size_t)r0*64 + lane] : bp;
    xs1 = (r1 >= 0) ? XW4[(size_t)r1*64 + lane] : bp;
  }
  float c = sigm(xs0.x)*ftanh(xs0.z);
  float h = sigm(xs0.w)*ftanh(c);
  shh[w][lane] = h;
  #pragma unroll
  for (int t=1;t<SEQL;t++){
    if (t==1){ int ri = node-2; xs2 = (ri>=0) ? XW4[(size_t)ri*64+lane] : bp; }
    if (t==2){ int ri = node-1; xs3 = (ri>=0) ? XW4[(size_t)ri*64+lane] : bp; }
    if (t==3){ xs4 = XW4[(size_t)node*64 + lane]; }
    // same-wave LDS RAW: wait for our h write, then broadcast-read
    asm volatile("s_waitcnt lgkmcnt(0)" ::: "memory");
    __builtin_amdgcn_sched_barrier(0);
    vf4 aA={0,0,0,0}, aB={0,0,0,0};
    #pragma unroll
    for (int j=0;j<16;j++){
      vf4 hv = *(const vf4*)&shh[w][j*4];
      aA += hv*wh[j];
      aB += hv*wh[16+j];
    }
    int pb = t & 1;
    gx[pb][2*w+0][lane] = aA.x+aA.y+aA.z+aA.w;
    gx[pb][2*w+1][lane] = aB.x+aB.y+aB.z+aB.w;
    __syncthreads();                   // ONE barrier per step (gx parity-dbuf kills WAR)
    vf4 xv = (t==1) ? xs1 : (t==2) ? xs2 : (t==3) ? xs3 : xs4;
    float gi = gx[pb][0][lane] + xv.x;
    float gf = gx[pb][1][lane] + xv.y;
    float gg = gx[pb][2][lane] + xv.z;
    float go = gx[pb][3][lane] + xv.w;
    c = sigm(gf)*c + sigm(gi)*ftanh(gg);
    h = sigm(go)*ftanh(c);
    if (t < SEQL-1) shh[w][lane] = h;
  }
  if (w == 0){
    size_t o = scatter ? ((size_t)node*64 + lane) : ((size_t)task*64 + lane);
    dst[o] = h;
  }
}

// ==========================================================================
extern "C" void kernel_launch(void* const* d_in, const int* in_sizes, int n_in,
                              void* d_out, int out_size, void* d_ws, size_t ws_size,
                              hipStream_t stream) {
  const float* x   = (const float*)d_in[0];
  const int*   ei  = (const int*)d_in[1];
  const int*   row = ei;
  const int*   col = ei + EE;
  const void*  mp  = d_in[2];
  const float* W0  = (const float*)d_in[3];
  const float* b0  = (const float*)d_in[4];
  const float* W1  = (const float*)d_in[5];
  const float* b1  = (const float*)d_in[6];
  const float* pw  = (const float*)d_in[7];
  const float* Wu  = (const float*)d_in[8];
  const float* bu  = (const float*)d_in[9];
  const float* l0wih=(const float*)d_in[10];
  const float* l0whh=(const float*)d_in[11];
  const float* l0bih=(const float*)d_in[12];
  const float* l0bhh=(const float*)d_in[13];
  const float* lfwih=(const float*)d_in[14];
  const float* lfwhh=(const float*)d_in[15];
  const float* lfbih=(const float*)d_in[16];
  const float* lfbhh=(const float*)d_in[17];

  char* wp = (char*)d_ws;
  auto alloc = [&](size_t bytes)->char*{ char* p = wp; wp += ((bytes+255)/256)*256; return p; };
  float* A     = (float*)alloc((size_t)NN*64*4);   // h0 -> t2
  float* B     = (float*)alloc((size_t)NN*64*4);   // xo
  float* C     = (float*)alloc((size_t)NN*64*4);   // x1
  float* D     = (float*)alloc((size_t)NN*64*4);   // y
  float* Ebuf  = (float*)alloc((size_t)NN*64*4);   // hp -> up-GCN input
  float* Hbuf  = (float*)alloc((size_t)NN*64*4);   // LSTM0 compact output
  float* XW    = (float*)alloc((size_t)NN*256*4);  // gate-x precompute (51.2 MB)
  float* WT0   = (float*)alloc((size_t)256*64*4);
  float* WTf   = (float*)alloc((size_t)256*64*4);
  float* bs0   = (float*)alloc((size_t)256*4);
  float* bsf   = (float*)alloc((size_t)256*4);
  float* score = (float*)alloc((size_t)NN*4);
  float* dinv0 = (float*)alloc((size_t)NN*4);
  float* dinv1 = (float*)alloc((size_t)NN*4);
  unsigned long long* keys = (unsigned long long*)alloc((size_t)NN*8);
  int* degcnt  = (int*)alloc((size_t)NN*4);
  int* diagint = (int*)alloc((size_t)NN*4);
  int* ts      = (int*)alloc((size_t)NN*4);
  int* kp      = (int*)alloc((size_t)NN*4);
  int* mlist   = (int*)alloc((size_t)NN*4);
  int* minv    = (int*)alloc((size_t)NN*4);
  int* indptr  = (int*)alloc((size_t)(NN+1)*4);
  int* part    = (int*)alloc((size_t)NN*4);
  int* mpart   = (int*)alloc((size_t)NN*4);
  int* fillc   = (int*)alloc((size_t)NN*4);
  int* bsum    = (int*)alloc((size_t)256*4);
  int* mbsum   = (int*)alloc((size_t)256*4);
  int* csr_r   = (int*)alloc((size_t)EE*4);
  uint2* hash  = (uint2*)alloc((size_t)HASH_SIZE*8);
  unsigned* hist=(unsigned*)alloc((size_t)4*65536*4);
  unsigned* scal=(unsigned*)alloc(256);
  unsigned long long* selp = (unsigned long long*)(scal + 4);

  #define GRID1(n) dim3(((n)+255)/256), dim3(256), 0, stream
  #define GRIDW dim3((NN+3)/4), dim3(256), 0, stream

  // 1. merged init
  k_init<<<GRID1(HASH_SIZE)>>>(hash, hist, degcnt, diagint, fillc,
                               scal, selp, l0wih, l0bih, l0bhh, lfwih, lfbih, lfbhh,
                               WT0, WTf, bs0, bsf);
  // 2. degcnt + hash build + mask detect + GCN0 matmul
  k_phase2<<<GRID1(NN*16)>>>(row, col, (const int*)mp, degcnt, hash, scal, x, W0, A);
  // 3-4. DUAL prefix sum: indptr (+dinv0) AND sorted mask compaction (mlist/minv/M)
  k_psum1<<<dim3(PSB),dim3(256),0,stream>>>(degcnt, mp, scal, part, bsum, mpart, mbsum, dinv0);
  k_psum3<<<dim3(PSB),dim3(256),0,stream>>>(part, bsum, mpart, mbsum, mp, scal, indptr, mlist, minv);
  // 5. csr fill + A^2 diag
  k_phase4<<<GRID1(EE)>>>(row, col, indptr, fillc, csr_r, hash, diagint);

  // 6. GCN0 gather (+ fused TopK score/key + radix round-0 hist)
  g_gcn0<<<GRIDW>>>(indptr, csr_r, dinv0, A, b0, pw, C, keys, score, hist);

  // 7. TopK radix select (round-0 hist already done)
  k_pick<<<dim3(1),dim3(256),0,stream>>>(hist, selp, scal);
  for (int r2=1;r2<4;r2++){
    k_hist<<<GRID1(NN)>>>(keys, hist + r2*65536, selp, r2);
    k_pick<<<dim3(1),dim3(256),0,stream>>>(hist + r2*65536, selp, scal);
  }
  // 8-9. pooled degree pass 1, then pass2+dinv1 merged with hp matmul
  k_tsg<<<GRID1(NN)>>>(indptr, csr_r, keys, selp, kp, ts);
  k_csgmm<<<GRID1(NN*16+NN)>>>(indptr, csr_r, ts, diagint, kp, dinv1, C, W1, score, Ebuf);
  g_t2<<<GRIDW>>>(indptr, csr_r, dinv1, Ebuf, A);

  // 10. LSTM0 on x1 windows -> Hbuf (compact)
  k_xw<<<dim3(512),dim3(256),0,stream>>>(C, WT0, bs0, XW);
  k_rec<<<dim3(NN),dim3(128),0,stream>>>(XW, l0whh, bs0, mlist, scal, Hbuf, 0);

  // 11. y = res + up
  g_agg2y<<<GRIDW>>>(indptr, csr_r, A, Ebuf, dinv1, diagint, kp, b1, C, Hbuf, minv, D);

  // 12. up-GCN input matmul, then up-GCN -> xo (B) and d_out
  k_mm64v<<<GRID1(NN*16)>>>(D, Wu, Ebuf);
  g_up<<<GRIDW>>>(indptr, csr_r, dinv0, Ebuf, bu, B, (float*)d_out);

  // 13-14. final LSTM on xo windows, scatter into d_out masked rows
  k_xw<<<dim3(512),dim3(256),0,stream>>>(B, WTf, bsf, XW);
  k_rec<<<dim3(NN),dim3(128),0,stream>>>(XW, lfwhh, bsf, mlist, scal, (float*)d_out, 1);
  #undef GRIDW
  #undef GRID1
}

// Round 10
// 618.904 us; speedup vs baseline: 1.4120x; 1.4120x over previous
//
#include <hip/hip_runtime.h>
#include <math.h>

// Problem constants (fixed by reference setup)
#define NN 50000
#define EE 400000
#define CINV 32
#define KKEEP 25000          // ceil(0.5*N)
#define SEQL 5
#define HASH_BITS 20
#define HASH_SIZE (1u<<HASH_BITS)
#define HASH_MASK (HASH_SIZE-1u)
#define HEMPTY 0xFFFFFFFFu
#define PSB 196              // ceil(NN/256)

typedef float vf4 __attribute__((ext_vector_type(4)));

__device__ __forceinline__ float sigm(float x){ return __builtin_amdgcn_rcpf(1.f+__expf(-x)); }
__device__ __forceinline__ float ftanh(float x){ return 1.f - 2.f*__builtin_amdgcn_rcpf(1.f+__expf(2.f*x)); }

// ---------------- merged init (+ LSTM weight prep) ----------------
// WT/bsum are PERMUTED so k_xw emits XW interleaved: XW[n][ch*4+g].
__global__ void k_init(uint2* __restrict__ hash, unsigned* __restrict__ hist,
                       int* __restrict__ degcnt, int* __restrict__ diagint,
                       int* __restrict__ fillc,
                       unsigned* scal, unsigned long long* selp,
                       const float* __restrict__ w0, const float* __restrict__ b0i,
                       const float* __restrict__ b0h, const float* __restrict__ wf,
                       const float* __restrict__ bfi, const float* __restrict__ bfh,
                       float* __restrict__ WT0, float* __restrict__ WTf,
                       float* __restrict__ bs0, float* __restrict__ bsf){
  int i = blockIdx.x*256 + threadIdx.x;
  if (i < (int)HASH_SIZE) hash[i] = make_uint2(HEMPTY, 0u);
  if (i < 4*65536) hist[i] = 0u;
  if (i < NN){ degcnt[i]=0; diagint[i]=0; fillc[i]=0; }
  if (i < 256*64){
    int r = i>>6, k = i&63;
    int dst = k*256 + (r&63)*4 + (r>>6);   // [k][ch][gate]
    WT0[dst] = w0[i];
    WTf[dst] = wf[i];
  }
  if (i < 256){
    int dst = (i&63)*4 + (i>>6);           // [ch][gate]
    bs0[dst]=b0i[i]+b0h[i]; bsf[dst]=bfi[i]+bfh[i];
  }
  if (i == 0){ scal[0]=0u; scal[1]=0u; scal[3]=KKEEP; selp[0]=0ull; }
}

// ---------------- phase2: degcnt + hash build + mask detect + GCN0 matmul ----------------
__global__ void k_phase2(const int* __restrict__ row, const int* __restrict__ col,
                         const int* __restrict__ mp, int* __restrict__ degcnt,
                         uint2* __restrict__ tab, unsigned* scal,
                         const float* __restrict__ X, const float* __restrict__ W,
                         float* __restrict__ Y){
  int idx = blockIdx.x*256 + threadIdx.x;
  if (idx < EE){
    int c = col[idx];
    atomicAdd(&degcnt[c], 1);
    unsigned key = (unsigned)row[idx]*50000u + (unsigned)c;
    unsigned h = (key*2654435761u) >> (32-HASH_BITS);
    for(;;){
      unsigned old = atomicCAS(&tab[h].x, HEMPTY, key);
      if (old==HEMPTY || old==key){ atomicAdd(&tab[h].y, 1u); break; }
      h = (h+1)&HASH_MASK;
    }
  }
  if (idx < NN/4){ if ((unsigned)mp[idx] > 1u) atomicOr(&scal[1], 1u); }
  if (idx < NN*16){
    int i = idx>>4, fq = idx&15;
    const vf4* X4 = (const vf4*)&X[i*CINV];
    const vf4* W4 = (const vf4*)W;
    vf4 acc = {0.f,0.f,0.f,0.f};
    #pragma unroll
    for (int kq=0;kq<CINV/4;kq++){
      vf4 xv = X4[kq];
      #pragma unroll
      for (int u=0;u<4;u++) acc += xv[u] * W4[(kq*4+u)*16+fq];
    }
    ((vf4*)Y)[i*16+fq] = acc;
  }
}

// ---------------- DUAL prefix sum (indptr + SORTED mask compaction) + dinv0 ----------------
__global__ void k_psum1(const int* __restrict__ deg, const void* __restrict__ mp,
                        const unsigned* __restrict__ scal,
                        int* __restrict__ part, int* __restrict__ bsum,
                        int* __restrict__ mpart, int* __restrict__ mbsum,
                        float* __restrict__ dinv){
  __shared__ int sc[256];
  __shared__ int sm[256];
  int b = blockIdx.x, t = threadIdx.x, i = b*256+t;
  int v = (i<NN) ? deg[i] : 0;
  int mv = 0;
  if (i < NN){
    dinv[i] = rsqrtf((float)v + 2.0f);
    mv = scal[1] ? (int)(((const unsigned char*)mp)[i] != 0)
                 : (int)(((const int*)mp)[i] != 0);
  }
  sc[t] = v; sm[t] = mv; __syncthreads();
  for (int o=1;o<256;o<<=1){
    int x = (t>=o) ? sc[t-o] : 0;
    int y = (t>=o) ? sm[t-o] : 0;
    __syncthreads();
    sc[t] += x; sm[t] += y;
    __syncthreads();
  }
  if (i < NN){ part[i] = sc[t]-v; mpart[i] = sm[t]-mv; }
  if (t == 255){ bsum[b] = sc[255]; mbsum[b] = sm[255]; }
}
__global__ void k_psum3(const int* __restrict__ part, const int* __restrict__ bsum,
                        const int* __restrict__ mpart, const int* __restrict__ mbsum,
                        const void* __restrict__ mp, unsigned* __restrict__ scal,
                        int* __restrict__ indptr, int* __restrict__ mlist,
                        int* __restrict__ minv){
  __shared__ int sc[256];
  __shared__ int sm[256];
  int t = threadIdx.x;
  int v = (t<PSB) ? bsum[t] : 0;
  int w = (t<PSB) ? mbsum[t] : 0;
  sc[t] = v; sm[t] = w; __syncthreads();
  for (int o=1;o<256;o<<=1){
    int x = (t>=o) ? sc[t-o] : 0;
    int y = (t>=o) ? sm[t-o] : 0;
    __syncthreads();
    sc[t] += x; sm[t] += y;
    __syncthreads();
  }
  int bb = blockIdx.x;
  int ex  = sc[bb] - ((bb<PSB) ? bsum[bb] : 0);    // exclusive prefixes for this block
  int mex = sm[bb] - ((bb<PSB) ? mbsum[bb] : 0);
  int i = bb*256 + t;
  if (i < NN){
    indptr[i] = part[i] + ex;
    int mv = scal[1] ? (int)(((const unsigned char*)mp)[i] != 0)
                     : (int)(((const int*)mp)[i] != 0);
    if (mv){ int p = mpart[i] + mex; mlist[p] = i; minv[i] = p; }
    else minv[i] = -1;
  }
  if (i == 0){ indptr[NN] = EE; scal[0] = (unsigned)sm[255]; }
}

// ---------------- csr fill + A^2 diag ----------------
__global__ void k_phase4(const int* __restrict__ row, const int* __restrict__ col,
                         const int* __restrict__ indptr, int* __restrict__ fillc,
                         int* __restrict__ csr_r, const uint2* __restrict__ tab,
                         int* __restrict__ diagint){
  int idx = blockIdx.x*256 + threadIdx.x;
  if (idx >= EE) return;
  int r = row[idx], c = col[idx];
  int pos = indptr[c] + atomicAdd(&fillc[c], 1);
  csr_r[pos] = r;
  unsigned rkey = (unsigned)c*50000u + (unsigned)r;
  unsigned h = (rkey*2654435761u) >> (32-HASH_BITS);
  for(;;){
    unsigned kk = tab[h].x;
    if (kk==rkey){ atomicAdd(&diagint[r], (int)tab[h].y); break; }
    if (kk==HEMPTY) break;
    h = (h+1)&HASH_MASK;
  }
}

// ---------------- CSR gather GCN kernels (8-wide zero-padded, R16-proven) ----------------
__global__ void g_gcn0(const int* __restrict__ indptr, const int* __restrict__ csr_r,
                       const float* __restrict__ dinv, const float* __restrict__ H,
                       const float* __restrict__ b, const float* __restrict__ pw,
                       float* __restrict__ out, unsigned long long* __restrict__ keys,
                       float* __restrict__ score, unsigned* __restrict__ hist){
  int node = blockIdx.x*4 + (threadIdx.x>>6), lane = threadIdx.x&63;
  if (node >= NN) return;
  int s = __builtin_amdgcn_readfirstlane(indptr[node]);
  int e = __builtin_amdgcn_readfirstlane(indptr[node+1]);
  int deg = e - s;
  float a0=0.f,a1=0.f,a2=0.f,a3=0.f,a4=0.f,a5=0.f,a6=0.f,a7=0.f;
  for (int base=0; base<deg; base+=64){
    int take = min(64, deg-base);
    bool act = lane < take;
    int ii = act ? csr_r[s+base+lane] : 0;
    float dv = act ? dinv[ii] : 0.f;
    for (int j=0; j<take; j+=8){
      int   r0=__shfl(ii,j,64),   r1=__shfl(ii,j+1,64), r2=__shfl(ii,j+2,64), r3=__shfl(ii,j+3,64),
            r4=__shfl(ii,j+4,64), r5=__shfl(ii,j+5,64), r6=__shfl(ii,j+6,64), r7=__shfl(ii,j+7,64);
      float d0=__shfl(dv,j,64),   d1=__shfl(dv,j+1,64), d2=__shfl(dv,j+2,64), d3=__shfl(dv,j+3,64),
            d4=__shfl(dv,j+4,64), d5=__shfl(dv,j+5,64), d6=__shfl(dv,j+6,64), d7=__shfl(dv,j+7,64);
      a0 += d0*H[(size_t)r0*64+lane];
      a1 += d1*H[(size_t)r1*64+lane];
      a2 += d2*H[(size_t)r2*64+lane];
      a3 += d3*H[(size_t)r3*64+lane];
      a4 += d4*H[(size_t)r4*64+lane];
      a5 += d5*H[(size_t)r5*64+lane];
      a6 += d6*H[(size_t)r6*64+lane];
      a7 += d7*H[(size_t)r7*64+lane];
    }
  }
  float acc = ((a0+a1)+(a2+a3)) + ((a4+a5)+(a6+a7));
  float di = dinv[node];
  float v = di*acc + 2.f*di*di*H[(size_t)node*64+lane] + b[lane];
  float x1v = fmaxf(v, 0.f);
  out[(size_t)node*64+lane] = x1v;
  float pv = pw[lane];
  float nq = pv*pv;
  float dq = x1v*pv;
  for (int o=32;o;o>>=1){ nq += __shfl_down(nq, o, 64); dq += __shfl_down(dq, o, 64); }
  if (lane==0){
    float sv = tanhf(dq / sqrtf(nq));
    sv = sv + 0.0f;               // canonicalize -0 -> +0
    score[node] = sv;
    unsigned u = __float_as_uint(sv);
    unsigned asc = (u>>31) ? ~u : (u | 0x80000000u);
    unsigned desc = ~asc;
    keys[node] = (((unsigned long long)desc)<<32) | (unsigned)node;
    atomicAdd(&hist[desc>>16], 1u);      // radix round-0 histogram
  }
}
// t2: unconditional 8-wide (k_csgmm zero-fills dropped rows)
__global__ void g_t2(const int* __restrict__ indptr, const int* __restrict__ csr_r,
                     const float* __restrict__ dinv1, const float* __restrict__ hp,
                     float* __restrict__ t2){
  int node = blockIdx.x*4 + (threadIdx.x>>6), lane = threadIdx.x&63;
  if (node >= NN) return;
  int s = __builtin_amdgcn_readfirstlane(indptr[node]);
  int e = __builtin_amdgcn_readfirstlane(indptr[node+1]);
  int deg = e - s;
  float a0 = dinv1[node]*hp[(size_t)node*64+lane];   // self loop
  float a1=0.f,a2=0.f,a3=0.f,a4=0.f,a5=0.f,a6=0.f,a7=0.f;
  for (int base=0; base<deg; base+=64){
    int take = min(64, deg-base);
    bool act = lane < take;
    int ii = act ? csr_r[s+base+lane] : 0;
    float dv = act ? dinv1[ii] : 0.f;
    for (int j=0; j<take; j+=8){
      int   r0=__shfl(ii,j,64),   r1=__shfl(ii,j+1,64), r2=__shfl(ii,j+2,64), r3=__shfl(ii,j+3,64),
            r4=__shfl(ii,j+4,64), r5=__shfl(ii,j+5,64), r6=__shfl(ii,j+6,64), r7=__shfl(ii,j+7,64);
      float d0=__shfl(dv,j,64),   d1=__shfl(dv,j+1,64), d2=__shfl(dv,j+2,64), d3=__shfl(dv,j+3,64),
            d4=__shfl(dv,j+4,64), d5=__shfl(dv,j+5,64), d6=__shfl(dv,j+6,64), d7=__shfl(dv,j+7,64);
      a0 += d0*hp[(size_t)r0*64+lane];
      a1 += d1*hp[(size_t)r1*64+lane];
      a2 += d2*hp[(size_t)r2*64+lane];
      a3 += d3*hp[(size_t)r3*64+lane];
      a4 += d4*hp[(size_t)r4*64+lane];
      a5 += d5*hp[(size_t)r5*64+lane];
      a6 += d6*hp[(size_t)r6*64+lane];
      a7 += d7*hp[(size_t)r7*64+lane];
    }
  }
  t2[(size_t)node*64+lane] = ((a0+a1)+(a2+a3)) + ((a4+a5)+(a6+a7));
}
// ---------------- g_agg2m: agg2y (8-wide gather) + fused COALESCED up-matmul ----------------
// D row stays in registers; epilogue: Ebuf[node][lane] = sum_k D[k]*Wu[k][lane].
// Wu natural layout: per k the wave reads 256 B contiguous (L1-resident 16 KB);
// D[k] via per-wave LDS broadcast (same-wave RAW, lgkmcnt-ordered).
// In-place over hp is safe: block reads only its OWN hp row, before write.
// Replaces g_agg2y + k_mm64v (one launch + 25.6 MB D round-trip saved; R15
// decomposition evidenced the coalesced fusion at ~-4us on its own).
__global__ void g_agg2m(const int* __restrict__ indptr, const int* __restrict__ csr_r,
                        const float* __restrict__ t2, float* __restrict__ hp,
                        const float* __restrict__ dinv1, const int* __restrict__ diagint,
                        const int* __restrict__ kp, const float* __restrict__ b1,
                        const float* __restrict__ C, const float* __restrict__ Hbuf,
                        const int* __restrict__ minv, const float* __restrict__ Wu){
  __shared__ __align__(16) float shD[4][64];
  int wv = threadIdx.x>>6, lane = threadIdx.x&63;
  int node = blockIdx.x*4 + wv;
  if (node >= NN) return;
  int mv = minv[node];
  float base = (mv >= 0) ? Hbuf[(size_t)mv*64+lane] : C[(size_t)node*64+lane];
  float add = 0.f;
  if (kp[node]){
    int s = __builtin_amdgcn_readfirstlane(indptr[node]);
    int e = __builtin_amdgcn_readfirstlane(indptr[node+1]);
    int deg = e - s;
    float a0 = t2[(size_t)node*64+lane];             // self loop
    float a1=0.f,a2=0.f,a3=0.f,a4=0.f,a5=0.f,a6=0.f,a7=0.f;
    for (int bs2=0; bs2<deg; bs2+=64){
      int take = min(64, deg-bs2);
      bool act = lane < take;
      int ii = act ? csr_r[s+bs2+lane] : 0;
      float wvp = act ? 1.f : 0.f;                   // pad weight
      for (int j=0; j<take; j+=8){
        int   r0=__shfl(ii,j,64),   r1=__shfl(ii,j+1,64), r2=__shfl(ii,j+2,64), r3=__shfl(ii,j+3,64),
              r4=__shfl(ii,j+4,64), r5=__shfl(ii,j+5,64), r6=__shfl(ii,j+6,64), r7=__shfl(ii,j+7,64);
        float w0=__shfl(wvp,j,64),  w1=__shfl(wvp,j+1,64), w2=__shfl(wvp,j+2,64), w3=__shfl(wvp,j+3,64),
              w4=__shfl(wvp,j+4,64), w5=__shfl(wvp,j+5,64), w6=__shfl(wvp,j+6,64), w7=__shfl(wvp,j+7,64);
        a0 += w0*t2[(size_t)r0*64+lane];
        a1 += w1*t2[(size_t)r1*64+lane];
        a2 += w2*t2[(size_t)r2*64+lane];
        a3 += w3*t2[(size_t)r3*64+lane];
        a4 += w4*t2[(size_t)r4*64+lane];
        a5 += w5*t2[(size_t)r5*64+lane];
        a6 += w6*t2[(size_t)r6*64+lane];
        a7 += w7*t2[(size_t)r7*64+lane];
      }
    }
    float acc = ((a0+a1)+(a2+a3)) + ((a4+a5)+(a6+a7));
    float di = dinv1[node], hv = hp[(size_t)node*64+lane];
    float diag = (float)(diagint[node] + 1);
    float v = di*(acc - diag*di*hv) + 2.f*di*di*hv + b1[lane];
    add = fmaxf(v, 0.f);
  }
  float dval = base + add;
  shD[wv][lane] = dval;
  asm volatile("s_waitcnt lgkmcnt(0)" ::: "memory");
  __builtin_amdgcn_sched_barrier(0);
  float acc = 0.f;
  #pragma unroll 16
  for (int k=0;k<64;k++) acc += shD[wv][k] * Wu[k*64 + lane];
  hp[(size_t)node*64+lane] = acc;
}
__global__ void g_up(const int* __restrict__ indptr, const int* __restrict__ csr_r,
                     const float* __restrict__ dinv, const float* __restrict__ H,
                     const float* __restrict__ b, float* __restrict__ xo, float* __restrict__ out){
  int node = blockIdx.x*4 + (threadIdx.x>>6), lane = threadIdx.x&63;
  if (node >= NN) return;
  int s = __builtin_amdgcn_readfirstlane(indptr[node]);
  int e = __builtin_amdgcn_readfirstlane(indptr[node+1]);
  int deg = e - s;
  float a0=0.f,a1=0.f,a2=0.f,a3=0.f,a4=0.f,a5=0.f,a6=0.f,a7=0.f;
  for (int base=0; base<deg; base+=64){
    int take = min(64, deg-base);
    bool act = lane < take;
    int ii = act ? csr_r[s+base+lane] : 0;
    float dv = act ? dinv[ii] : 0.f;
    for (int j=0; j<take; j+=8){
      int   r0=__shfl(ii,j,64),   r1=__shfl(ii,j+1,64), r2=__shfl(ii,j+2,64), r3=__shfl(ii,j+3,64),
            r4=__shfl(ii,j+4,64), r5=__shfl(ii,j+5,64), r6=__shfl(ii,j+6,64), r7=__shfl(ii,j+7,64);
      float d0=__shfl(dv,j,64),   d1=__shfl(dv,j+1,64), d2=__shfl(dv,j+2,64), d3=__shfl(dv,j+3,64),
            d4=__shfl(dv,j+4,64), d5=__shfl(dv,j+5,64), d6=__shfl(dv,j+6,64), d7=__shfl(dv,j+7,64);
      a0 += d0*H[(size_t)r0*64+lane];
      a1 += d1*H[(size_t)r1*64+lane];
      a2 += d2*H[(size_t)r2*64+lane];
      a3 += d3*H[(size_t)r3*64+lane];
      a4 += d4*H[(size_t)r4*64+lane];
      a5 += d5*H[(size_t)r5*64+lane];
      a6 += d6*H[(size_t)r6*64+lane];
      a7 += d7*H[(size_t)r7*64+lane];
    }
  }
  float acc = ((a0+a1)+(a2+a3)) + ((a4+a5)+(a6+a7));
  float di = dinv[node];
  float v = di*acc + 2.f*di*di*H[(size_t)node*64+lane] + b[lane];
  xo[(size_t)node*64+lane] = v; out[(size_t)node*64+lane] = v;
}

// ---------------- TopK radix select (round 0 hist fused into g_gcn0) ----------------
__global__ void k_hist(const unsigned long long* __restrict__ keys, unsigned* __restrict__ hist,
                       const unsigned long long* __restrict__ selp, int round){
  int i = blockIdx.x*256 + threadIdx.x;
  if (i >= NN) return;
  unsigned long long key = keys[i];
  int shift = 48 - 16*round;
  if ((key>>(shift+16)) == selp[0])
    atomicAdd(&hist[(unsigned)((key>>shift)&0xFFFFull)], 1u);
}
__global__ void k_pick(const unsigned* __restrict__ hist, unsigned long long* selp, unsigned* scal){
  __shared__ unsigned csum[256];
  __shared__ unsigned bins[256];
  __shared__ int schunk;
  int t = threadIdx.x;
  const uint4* h4 = (const uint4*)(hist + t*256);
  unsigned s = 0;
  #pragma unroll 8
  for (int j=0;j<64;j++){ uint4 v = h4[j]; s += v.x+v.y+v.z+v.w; }
  csum[t] = s;
  __syncthreads();
  if (t==0){
    unsigned rem = scal[3];
    int chunk = 255;
    for (int c2=0;c2<256;c2++){ unsigned cc=csum[c2]; if (rem>cc) rem-=cc; else { chunk=c2; break; } }
    schunk = chunk; scal[3] = rem;
  }
  __syncthreads();
  bins[t] = hist[schunk*256 + t];
  __syncthreads();
  if (t==0){
    unsigned rem = scal[3];
    int bin = schunk*256 + 255;
    for (int b=0;b<256;b++){ unsigned hv=bins[b]; if (rem>hv) rem-=hv; else { bin = schunk*256 + b; break; } }
    selp[0] = (selp[0]<<16) | (unsigned long long)(unsigned)bin;
    scal[3] = rem;
  }
}
// pooled degree pass 1 (CSR gather): kp[i]; ts[i] = sum_{r->i} kp[r] + kp[i]
__global__ void k_tsg(const int* __restrict__ indptr, const int* __restrict__ csr_r,
                      const unsigned long long* __restrict__ keys,
                      const unsigned long long* __restrict__ selp,
                      int* __restrict__ kp, int* __restrict__ ts){
  int i = blockIdx.x*256 + threadIdx.x;
  if (i >= NN) return;
  unsigned long long sp = selp[0];
  int s = indptr[i], e = indptr[i+1];
  int self = (keys[i] <= sp) ? 1 : 0;
  kp[i] = self;
  int acc = self;
  for (int j=s;j<e;j++) acc += (keys[csr_r[j]] <= sp) ? 1 : 0;
  ts[i] = acc;
}
// pooled degree pass 2 + dinv1 MERGED with hp = (x1*score)@W1
// Dropped nodes WRITE ZERO rows (enables unguarded g_t2 gather).
__global__ void k_csgmm(const int* __restrict__ indptr, const int* __restrict__ csr_r,
                        const int* __restrict__ ts, const int* __restrict__ diagint,
                        const int* __restrict__ kp, float* __restrict__ dinv1,
                        const float* __restrict__ X, const float* __restrict__ W,
                        const float* __restrict__ sc, float* __restrict__ Y){
  int idx = blockIdx.x*256 + threadIdx.x;
  if (idx < NN*16){
    int i = idx>>4, fq = idx&15;
    if (!kp[i]){ vf4 z = {0.f,0.f,0.f,0.f}; ((vf4*)Y)[i*16+fq] = z; return; }
    const vf4* X4 = (const vf4*)&X[i*64];
    const vf4* W4 = (const vf4*)W;
    vf4 acc = {0.f,0.f,0.f,0.f};
    #pragma unroll
    for (int kq=0;kq<16;kq++){
      vf4 xv = X4[kq];
      #pragma unroll
      for (int u=0;u<4;u++) acc += xv[u] * W4[(kq*4+u)*16+fq];
    }
    acc *= sc[i];
    ((vf4*)Y)[i*16+fq] = acc;
  } else {
    int i = idx - NN*16;
    if (i >= NN) return;
    int s = indptr[i], e = indptr[i+1];
    int acc = ts[i];
    for (int j=s;j<e;j++) acc += ts[csr_r[j]];
    dinv1[i] = kp[i] ? rsqrtf((float)(acc - diagint[i] - 1) + 2.0f) : 0.f;
  }
}

// ---------------- LSTM part 1: XW[n] = src[n] @ W_ih^T + (b_ih+b_hh) ----------------
__global__ __launch_bounds__(256) void k_xw(const float* __restrict__ src,
        const float* __restrict__ WT, const float* __restrict__ bsum,
        float* __restrict__ XW){
  __shared__ vf4 Wl[4096];              // 64 KB
  int t = threadIdx.x;
  const vf4* Wg = (const vf4*)WT;
  for (int u=t; u<4096; u+=256) Wl[u] = Wg[u];
  int fq = t & 63, wv = t >> 6;
  vf4 bias = ((const vf4*)bsum)[fq];
  __syncthreads();
  for (int g = blockIdx.x*4 + wv; g < NN/4; g += gridDim.x*4){
    int n0 = g*4;
    const vf4* X4 = (const vf4*)&src[(size_t)n0*64];   // 4 rows x 16 vf4
    vf4 a0=bias, a1=bias, a2=bias, a3=bias;
    #pragma unroll 4
    for (int kq=0;kq<16;kq++){
      vf4 x0 = X4[kq], x1 = X4[16+kq], x2 = X4[32+kq], x3 = X4[48+kq];
      vf4 w0 = Wl[(kq*4+0)*64+fq];
      vf4 w1 = Wl[(kq*4+1)*64+fq];
      vf4 w2 = Wl[(kq*4+2)*64+fq];
      vf4 w3 = Wl[(kq*4+3)*64+fq];
      a0 += x0.x*w0 + x0.y*w1 + x0.z*w2 + x0.w*w3;
      a1 += x1.x*w0 + x1.y*w1 + x1.z*w2 + x1.w*w3;
      a2 += x2.x*w0 + x2.y*w1 + x2.z*w2 + x2.w*w3;
      a3 += x3.x*w0 + x3.y*w1 + x3.z*w2 + x3.w*w3;
    }
    vf4* Y = (vf4*)XW;
    Y[(size_t)n0*64 + fq]       = a0;
    Y[(size_t)n0*64 + 64 + fq]  = a1;
    Y[(size_t)n0*64 + 128 + fq] = a2;
    Y[(size_t)n0*64 + 192 + fq] = a3;
  }
}

// ---------------- LSTM part 2: recurrence (hh-half only) ----------------
// R12-proven: XW interleaved dwordx4 reads, deep prefetch, one task/block.
// R17: mlist SORTED -> per-block windows overlap & stream (k_rec 90->78).
__global__ __launch_bounds__(256) void k_rec(const float* __restrict__ XW,
        const float* __restrict__ whh, const float* __restrict__ bsum,
        const int* __restrict__ mlist, const unsigned* __restrict__ scal,
        float* __restrict__ dst, int scatter){
  int M = (int)scal[0];
  if (M < 0 || M > NN) M = 0;          // defensive (rocprof replay poisons scal)
  int task = blockIdx.x;
  if (task*4 >= M) return;             // block-uniform early exit
  int w = threadIdx.x>>6, lane = threadIdx.x&63;
  int r = w*64 + lane;
  const vf4* g4 = (const vf4*)&whh[(size_t)r*64];
  vf4 wh[16];
  #pragma unroll
  for (int j=0;j<16;j++) wh[j] = g4[j];
  __shared__ float sh[4][64];
  __shared__ float gates[4][4][64];
  int m = task*4 + w;
  bool valid = (m < M);
  int node = mlist[valid ? m : (M-1)];
  node = min(max(node, 0), NN-1);      // defensive vs poisoned mlist in replay
  const vf4* XW4 = (const vf4*)XW;
  vf4 bp = ((const vf4*)bsum)[lane];
  vf4 xs0, xs1, xs2, xs3, xs4;
  {
    int r0 = node - 4, r1 = node - 3;
    xs0 = (r0 >= 0) ? XW4[(size_t)r0*64 + lane] : bp;
    xs1 = (r1 >= 0) ? XW4[(size_t)r1*64 + lane] : bp;
  }
  float c, h;
  c = sigm(xs0.x)*ftanh(xs0.z);
  h = sigm(xs0.w)*ftanh(c);
  sh[w][lane] = h;
  __syncthreads();
  #pragma unroll
  for (int t=1;t<SEQL;t++){
    if (t==1){ int ri = node-2; xs2 = (ri>=0) ? XW4[(size_t)ri*64+lane] : bp; }
    if (t==2){ int ri = node-1; xs3 = (ri>=0) ? XW4[(size_t)ri*64+lane] : bp; }
    if (t==3){ xs4 = XW4[(size_t)node*64 + lane]; }
    vf4 a0={0,0,0,0}, a1={0,0,0,0}, a2={0,0,0,0}, a3={0,0,0,0};
    #pragma unroll
    for (int j=0;j<16;j++){
      vf4 wj = wh[j];
      a0 += (*(const vf4*)&sh[0][j*4]) * wj;
      a1 += (*(const vf4*)&sh[1][j*4]) * wj;
      a2 += (*(const vf4*)&sh[2][j*4]) * wj;
      a3 += (*(const vf4*)&sh[3][j*4]) * wj;
    }
    gates[0][w][lane] = a0.x+a0.y+a0.z+a0.w;
    gates[1][w][lane] = a1.x+a1.y+a1.z+a1.w;
    gates[2][w][lane] = a2.x+a2.y+a2.z+a2.w;
    gates[3][w][lane] = a3.x+a3.y+a3.z+a3.w;
    __syncthreads();
    vf4 xv = (t==1) ? xs1 : (t==2) ? xs2 : (t==3) ? xs3 : xs4;
    float gi = gates[w][0][lane] + xv.x;
    float gf = gates[w][1][lane] + xv.y;
    float gg = gates[w][2][lane] + xv.z;
    float go = gates[w][3][lane] + xv.w;
    c = sigm(gf)*c + sigm(gi)*ftanh(gg);
    h = sigm(go)*ftanh(c);
    sh[w][lane] = h;
    __syncthreads();
  }
  if (valid){
    size_t o = scatter ? ((size_t)node*64 + lane) : ((size_t)m*64 + lane);
    dst[o] = h;
  }
}

// ==========================================================================
extern "C" void kernel_launch(void* const* d_in, const int* in_sizes, int n_in,
                              void* d_out, int out_size, void* d_ws, size_t ws_size,
                              hipStream_t stream) {
  const float* x   = (const float*)d_in[0];
  const int*   ei  = (const int*)d_in[1];
  const int*   row = ei;
  const int*   col = ei + EE;
  const void*  mp  = d_in[2];
  const float* W0  = (const float*)d_in[3];
  const float* b0  = (const float*)d_in[4];
  const float* W1  = (const float*)d_in[5];
  const float* b1  = (const float*)d_in[6];
  const float* pw  = (const float*)d_in[7];
  const float* Wu  = (const float*)d_in[8];
  const float* bu  = (const float*)d_in[9];
  const float* l0wih=(const float*)d_in[10];
  const float* l0whh=(const float*)d_in[11];
  const float* l0bih=(const float*)d_in[12];
  const float* l0bhh=(const float*)d_in[13];
  const float* lfwih=(const float*)d_in[14];
  const float* lfwhh=(const float*)d_in[15];
  const float* lfbih=(const float*)d_in[16];
  const float* lfbhh=(const float*)d_in[17];

  char* wp = (char*)d_ws;
  auto alloc = [&](size_t bytes)->char*{ char* p = wp; wp += ((bytes+255)/256)*256; return p; };
  float* A     = (float*)alloc((size_t)NN*64*4);   // h0 -> t2
  float* B     = (float*)alloc((size_t)NN*64*4);   // xo
  float* C     = (float*)alloc((size_t)NN*64*4);   // x1
  float* Ebuf  = (float*)alloc((size_t)NN*64*4);   // hp -> up-GCN input (in-place)
  float* Hbuf  = (float*)alloc((size_t)NN*64*4);   // LSTM0 compact output
  float* XW    = (float*)alloc((size_t)NN*256*4);  // gate-x precompute (51.2 MB)
  float* WT0   = (float*)alloc((size_t)256*64*4);
  float* WTf   = (float*)alloc((size_t)256*64*4);
  float* bs0   = (float*)alloc((size_t)256*4);
  float* bsf   = (float*)alloc((size_t)256*4);
  float* score = (float*)alloc((size_t)NN*4);
  float* dinv0 = (float*)alloc((size_t)NN*4);
  float* dinv1 = (float*)alloc((size_t)NN*4);
  unsigned long long* keys = (unsigned long long*)alloc((size_t)NN*8);
  int* degcnt  = (int*)alloc((size_t)NN*4);
  int* diagint = (int*)alloc((size_t)NN*4);
  int* ts      = (int*)alloc((size_t)NN*4);
  int* kp      = (int*)alloc((size_t)NN*4);
  int* mlist   = (int*)alloc((size_t)NN*4);
  int* minv    = (int*)alloc((size_t)NN*4);
  int* indptr  = (int*)alloc((size_t)(NN+1)*4);
  int* part    = (int*)alloc((size_t)NN*4);
  int* mpart   = (int*)alloc((size_t)NN*4);
  int* fillc   = (int*)alloc((size_t)NN*4);
  int* bsum    = (int*)alloc((size_t)256*4);
  int* mbsum   = (int*)alloc((size_t)256*4);
  int* csr_r   = (int*)alloc((size_t)EE*4);
  uint2* hash  = (uint2*)alloc((size_t)HASH_SIZE*8);
  unsigned* hist=(unsigned*)alloc((size_t)4*65536*4);
  unsigned* scal=(unsigned*)alloc(256);
  unsigned long long* selp = (unsigned long long*)(scal + 4);

  #define GRID1(n) dim3(((n)+255)/256), dim3(256), 0, stream
  #define GRIDW dim3((NN+3)/4), dim3(256), 0, stream

  // 1. merged init
  k_init<<<GRID1(HASH_SIZE)>>>(hash, hist, degcnt, diagint, fillc,
                               scal, selp, l0wih, l0bih, l0bhh, lfwih, lfbih, lfbhh,
                               WT0, WTf, bs0, bsf);
  // 2. degcnt + hash build + mask detect + GCN0 matmul
  k_phase2<<<GRID1(NN*16)>>>(row, col, (const int*)mp, degcnt, hash, scal, x, W0, A);
  // 3-4. DUAL prefix sum: indptr (+dinv0) AND sorted mask compaction (mlist/minv/M)
  k_psum1<<<dim3(PSB),dim3(256),0,stream>>>(degcnt, mp, scal, part, bsum, mpart, mbsum, dinv0);
  k_psum3<<<dim3(PSB),dim3(256),0,stream>>>(part, bsum, mpart, mbsum, mp, scal, indptr, mlist, minv);
  // 5. csr fill + A^2 diag
  k_phase4<<<GRID1(EE)>>>(row, col, indptr, fillc, csr_r, hash, diagint);

  // 6. GCN0 gather (+ fused TopK score/key + radix round-0 hist)
  g_gcn0<<<GRIDW>>>(indptr, csr_r, dinv0, A, b0, pw, C, keys, score, hist);

  // 7. TopK radix select (round-0 hist already done)
  k_pick<<<dim3(1),dim3(256),0,stream>>>(hist, selp, scal);
  for (int r2=1;r2<4;r2++){
    k_hist<<<GRID1(NN)>>>(keys, hist + r2*65536, selp, r2);
    k_pick<<<dim3(1),dim3(256),0,stream>>>(hist + r2*65536, selp, scal);
  }
  // 8-9. pooled degree pass 1, then pass2+dinv1 merged with hp matmul
  k_tsg<<<GRID1(NN)>>>(indptr, csr_r, keys, selp, kp, ts);
  k_csgmm<<<GRID1(NN*16+NN)>>>(indptr, csr_r, ts, diagint, kp, dinv1, C, W1, score, Ebuf);
  g_t2<<<GRIDW>>>(indptr, csr_r, dinv1, Ebuf, A);

  // 10. LSTM0 on x1 windows -> Hbuf (compact)
  k_xw<<<dim3(512),dim3(256),0,stream>>>(C, WT0, bs0, XW);
  k_rec<<<dim3(12500),dim3(256),0,stream>>>(XW, l0whh, bs0, mlist, scal, Hbuf, 0);

  // 11. y = res + up, fused with COALESCED up-matmul epilogue (Ebuf in-place)
  g_agg2m<<<GRIDW>>>(indptr, csr_r, A, Ebuf, dinv1, diagint, kp, b1, C, Hbuf, minv, Wu);

  // 12. up-GCN -> xo (B) and d_out
  g_up<<<GRIDW>>>(indptr, csr_r, dinv0, Ebuf, bu, B, (float*)d_out);

  // 13-14. final LSTM on xo windows, scatter into d_out masked rows
  k_xw<<<dim3(512),dim3(256),0,stream>>>(B, WTf, bsf, XW);
  k_rec<<<dim3(12500),dim3(256),0,stream>>>(XW, lfwhh, bsf, mlist, scal, (float*)d_out, 1);
  #undef GRIDW
  #undef GRID1
}